// Round 10
// baseline (116.432 us; speedup 1.0000x reference)
//
#include <hip/hip_runtime.h>
#include <hip/hip_bf16.h>
#include <cmath>

// SSIM loss via MFMA, round 10: 3-stage load pipeline + packed cvt + fused finale.
// H pass: 16x16x32 bf16 MFMA (A=data rows, B=banded Gaussian W).
// H's D-layout (lane: rows 4g+i, col m) IS the B-frag layout of a K=16 MFMA
// (lane: k=4g+j, col m), so V = 2 chained mfma_16x16x16_bf16 per quantity with
// B-frags straight from H result registers. No hq LDS, no mid-kernel barrier.
// vs round 9: pk2 built from plain __bf16 casts + shift/or (bit_cast of
// __hip_bfloat162 is ill-formed: non-trivially-copyable). Compiler fuses the
// scalar casts into v_cvt_pk_bf16_f32 on its own (learn_hip m240).

#define IMG   512
#define ODIM  502            // 512 - 11 + 1
#define SC    16             // strip cols (per wave)
#define BR    128            // strip rows
#define WPB   4              // waves per block
#define BC    (SC * WPB)     // 64 block cols
#define GX    8              // 512/64
#define GY    4              // 512/128
#define NC    64             // batch*channels
#define NBLK  (GX * GY * NC) // 2048
#define NVT   8              // V tiles per strip (8*16 = 128 rows)
#define NHT   9              // H tiles per strip

typedef float          f32x4  __attribute__((ext_vector_type(4)));
typedef __bf16         bf16x8 __attribute__((ext_vector_type(8)));
typedef __bf16         bf16x4 __attribute__((ext_vector_type(4)));
typedef short          s16x4  __attribute__((ext_vector_type(4)));
typedef unsigned int   u32x2  __attribute__((ext_vector_type(2)));
typedef unsigned int   u32x4  __attribute__((ext_vector_type(4)));

union F8 { bf16x8 v; u32x4 q; };
union F4 { bf16x4 v; s16x4 s; u32x2 q; };

__device__ __forceinline__ unsigned short bfbits(float f) {
    __bf16 h = (__bf16)f;
    return __builtin_bit_cast(unsigned short, h);
}
// two f32 -> packed bf16x2 in one u32 (compiler fuses to v_cvt_pk_bf16_f32)
__device__ __forceinline__ unsigned pk2(float lo, float hi) {
    return ((unsigned)bfbits(hi) << 16) | (unsigned)bfbits(lo);
}

__device__ __forceinline__ f32x4 mfma16(const F4& a, const F4& b, f32x4 c) {
    return __builtin_amdgcn_mfma_f32_16x16x16bf16_1k(a.s, b.s, c, 0, 0, 0);
}

struct GaussW { float g[11]; };
struct Raw { f32x4 a0, a1, b0, b1; };

__global__ __launch_bounds__(256, 4) void ssim_mfma_kernel(
    const float* __restrict__ X, const float* __restrict__ Y,
    float* __restrict__ partial, unsigned* __restrict__ counter,
    float* __restrict__ out, GaussW gw)
{
    __shared__ unsigned short wl[16][40];   // band weights: wl[m][k] = w[k-m]
    __shared__ float wsum[WPB];
    __shared__ double sd[256];
    __shared__ int lastFlag;

    const int tid  = threadIdx.x;
    const int lane = tid & 63;
    const int wave = tid >> 6;
    const int m    = lane & 15;
    const int g    = lane >> 4;

    // ---- weight band LUT (1.25 KB, filled once) ----
    for (int t = tid; t < 16 * 40; t += 256) {
        const int mm = t / 40, kk = t - 40 * mm;
        const int d  = kk - mm;
        wl[mm][kk] = bfbits((kk < 32 && d >= 0 && d < 11) ? gw.g[d] : 0.f);
    }
    __syncthreads();

    const int gx0 = blockIdx.x * BC + SC * wave;   // this wave's strip
    const int gy0 = blockIdx.y * BR;
    const int nc  = blockIdx.z;
    const float* __restrict__ Xp = X + (size_t)nc * IMG * IMG;
    const float* __restrict__ Yp = Y + (size_t)nc * IMG * IMG;

    F8 wf;  wf.q  = *(const u32x4*)&wl[m][8 * g];       // H B-frag: w[8g+j - m]
    F4 wa0; wa0.q = *(const u32x2*)&wl[m][4 * g];       // V A chunk0: w[4g+j - m]
    F4 wa1; wa1.q = *(const u32x2*)&wl[m][16 + 4 * g];  // V A chunk1: w[16+4g+j - m]
    const f32x4 z = {0.f, 0.f, 0.f, 0.f};

    const int cs = min(gx0 + 8 * g, IMG - 8);   // clamped cols feed only masked
                                                // outputs (band is zero there)

    auto loadRaw = [&](Raw& r, int rt) {
        const int gy = min(gy0 + 16 * rt + m, IMG - 1);
        const float* xr = Xp + gy * IMG + cs;
        const float* yr = Yp + gy * IMG + cs;
        r.a0 = *(const f32x4*)xr;  r.a1 = *(const f32x4*)(xr + 4);
        r.b0 = *(const f32x4*)yr;  r.b1 = *(const f32x4*)(yr + 4);
    };

    // H tile from raw regs: hd[q] <- lane (m,g) holds Hq[..16rt+4g+i][gx0+m]
    auto mfmaH = [&](F4 (&hd)[5], const Raw& r) {
        F8 fx, fy, fxx, fyy, fxy;
        fx.q  = u32x4{pk2(r.a0[0], r.a0[1]), pk2(r.a0[2], r.a0[3]),
                      pk2(r.a1[0], r.a1[1]), pk2(r.a1[2], r.a1[3])};
        fy.q  = u32x4{pk2(r.b0[0], r.b0[1]), pk2(r.b0[2], r.b0[3]),
                      pk2(r.b1[0], r.b1[1]), pk2(r.b1[2], r.b1[3])};
        fxx.q = u32x4{pk2(r.a0[0]*r.a0[0], r.a0[1]*r.a0[1]),
                      pk2(r.a0[2]*r.a0[2], r.a0[3]*r.a0[3]),
                      pk2(r.a1[0]*r.a1[0], r.a1[1]*r.a1[1]),
                      pk2(r.a1[2]*r.a1[2], r.a1[3]*r.a1[3])};
        fyy.q = u32x4{pk2(r.b0[0]*r.b0[0], r.b0[1]*r.b0[1]),
                      pk2(r.b0[2]*r.b0[2], r.b0[3]*r.b0[3]),
                      pk2(r.b1[0]*r.b1[0], r.b1[1]*r.b1[1]),
                      pk2(r.b1[2]*r.b1[2], r.b1[3]*r.b1[3])};
        fxy.q = u32x4{pk2(r.a0[0]*r.b0[0], r.a0[1]*r.b0[1]),
                      pk2(r.a0[2]*r.b0[2], r.a0[3]*r.b0[3]),
                      pk2(r.a1[0]*r.b1[0], r.a1[1]*r.b1[1]),
                      pk2(r.a1[2]*r.b1[2], r.a1[3]*r.b1[3])};
        const f32x4 dX  = __builtin_amdgcn_mfma_f32_16x16x32_bf16(fx.v,  wf.v, z, 0, 0, 0);
        const f32x4 dY  = __builtin_amdgcn_mfma_f32_16x16x32_bf16(fy.v,  wf.v, z, 0, 0, 0);
        const f32x4 dXX = __builtin_amdgcn_mfma_f32_16x16x32_bf16(fxx.v, wf.v, z, 0, 0, 0);
        const f32x4 dYY = __builtin_amdgcn_mfma_f32_16x16x32_bf16(fyy.v, wf.v, z, 0, 0, 0);
        const f32x4 dXY = __builtin_amdgcn_mfma_f32_16x16x32_bf16(fxy.v, wf.v, z, 0, 0, 0);
        hd[0].q = u32x2{pk2(dX[0],  dX[1]),  pk2(dX[2],  dX[3])};
        hd[1].q = u32x2{pk2(dY[0],  dY[1]),  pk2(dY[2],  dY[3])};
        hd[2].q = u32x2{pk2(dXX[0], dXX[1]), pk2(dXX[2], dXX[3])};
        hd[3].q = u32x2{pk2(dYY[0], dYY[1]), pk2(dYY[2], dYY[3])};
        hd[4].q = u32x2{pk2(dXY[0], dXY[1]), pk2(dXY[2], dXY[3])};
    };

    // ---- 3-stage pipeline: load(t+2) | H-MFMA(t+1) | V(t) ----
    Raw raw[2];
    F4  hh[2][5];
    loadRaw(raw[0], 0);
    loadRaw(raw[1], 1);
    mfmaH(hh[0], raw[0]);

    float acc = 0.f;
#pragma unroll
    for (int vt = 0; vt < NVT; ++vt) {
        if (vt + 2 < NHT) loadRaw(raw[vt & 1], vt + 2);     // folds at unroll
        mfmaH(hh[(vt + 1) & 1], raw[(vt + 1) & 1]);
        const F4 (&h0)[5] = hh[vt & 1];
        const F4 (&h1)[5] = hh[(vt + 1) & 1];

        f32x4 e[5];
#pragma unroll
        for (int q = 0; q < 5; ++q) {
            e[q] = mfma16(wa1, h1[q], z);
            e[q] = mfma16(wa0, h0[q], e[q]);
        }
        const float C1 = 1e-4f, C2 = 9e-4f;
#pragma unroll
        for (int i = 0; i < 4; ++i) {
            const int gy = gy0 + 16 * vt + 4 * g + i;
            const int gx = gx0 + m;
            const float mX = e[0][i], mY = e[1][i];
            const float muXX = mX * mX;
            const float muYY = mY * mY;
            const float muXY = mX * mY;
            const float sXX = e[2][i] - muXX;
            const float sYY = e[3][i] - muYY;
            const float sXY = e[4][i] - muXY;
            const float num = (2.f * muXY + C1) * (2.f * sXY + C2);
            const float den = (muXX + muYY + C1) * (sXX + sYY + C2);
            const float val = __fdividef(num, den);
            if (gy < ODIM && gx < ODIM) acc += val;
        }
    }

    // ---- deterministic block reduction ----
#pragma unroll
    for (int off = 32; off > 0; off >>= 1)
        acc += __shfl_down(acc, off, 64);

    if (lane == 0) wsum[wave] = acc;
    __syncthreads();
    const int bid = ((int)blockIdx.z * gridDim.y + blockIdx.y) * gridDim.x + blockIdx.x;
    if (tid == 0) {
        const float tsum = (wsum[0] + wsum[1]) + (wsum[2] + wsum[3]);
        partial[bid] = tsum;
        __threadfence();                           // publish partial
        const unsigned prev = atomicAdd(counter, 1u);
        lastFlag = (prev == NBLK - 1) ? 1 : 0;
    }
    __syncthreads();

    // ---- last block: fixed-order f64 reduction of all partials ----
    if (lastFlag) {
        __threadfence();                           // acquire
        const volatile float* vp = (const volatile float*)partial;
        double local = 0.0;
#pragma unroll
        for (int i = 0; i < NBLK / 256; ++i)
            local += (double)vp[tid * (NBLK / 256) + i];
        sd[tid] = local;
        __syncthreads();
        for (int s = 128; s > 0; s >>= 1) {
            if (tid < s) sd[tid] += sd[tid + s];
            __syncthreads();
        }
        if (tid == 0) {
            const double cnt = (double)NC * (double)ODIM * (double)ODIM;
            out[0] = (float)(1.0 - sd[0] / cnt);
        }
    }
}

extern "C" void kernel_launch(void* const* d_in, const int* in_sizes, int n_in,
                              void* d_out, int out_size, void* d_ws, size_t ws_size,
                              hipStream_t stream) {
    const float* X = (const float*)d_in[0];
    const float* Y = (const float*)d_in[1];
    float* out = (float*)d_out;
    float* partial = (float*)d_ws;                    // NBLK floats
    unsigned* counter = (unsigned*)((char*)d_ws + NBLK * sizeof(float));

    // counter must start at 0 every call (ws is poisoned, not re-poisoned):
    // in-graph async memset, runs before the kernel on each replay.
    (void)hipMemsetAsync(counter, 0, sizeof(unsigned), stream);

    // Gaussian taps in float64 -> f32 (matches numpy reference construction).
    GaussW gw;
    {
        double gd[11], s = 0.0;
        for (int i = 0; i < 11; ++i) {
            const double x = (double)(i - 5);
            gd[i] = std::exp(-(x * x) / (2.0 * 1.5 * 1.5));
            s += gd[i];
        }
        for (int i = 0; i < 11; ++i) gw.g[i] = (float)(gd[i] / s);
    }

    dim3 grid(GX, GY, NC);
    ssim_mfma_kernel<<<grid, 256, 0, stream>>>(X, Y, partial, counter, out, gw);
}

// Round 11
// 47.094 us; speedup vs baseline: 2.4723x; 2.4723x over previous
//
#include <hip/hip_runtime.h>
#include <hip/hip_bf16.h>
#include <cmath>

// SSIM loss via MFMA, round 11: round-8 structure + scratch-proof prefetch.
// H pass: 16x16x32 bf16 MFMA (A=data rows, B=banded Gaussian W).
// H's D-layout (lane: rows 4g+i, col m) IS the B-frag layout of a K=16 MFMA
// (lane: k=4g+j, col m), so V = 2 chained mfma_16x16x16_bf16 per quantity with
// B-frags straight from H result registers. No hq LDS, no mid-kernel barrier.
// vs round 10 (which regressed 2.5x): the Raw raw[2] array + by-reference
// lambda binding sent raw tiles to SCRATCH (rule #20: VGPR 36, VALUBusy 19%,
// all pipes idle). Now raw tiles are eight NAMED f32x4 vars passed BY VALUE;
// the vt loop is hand-written with literal indices (A/B role swap macros).
// Fragment construction back to union element writes (round-8-proven codegen).

#define IMG   512
#define ODIM  502            // 512 - 11 + 1
#define SC    16             // strip cols (per wave)
#define BR    128            // strip rows
#define WPB   4              // waves per block
#define BC    (SC * WPB)     // 64 block cols
#define GX    8              // 512/64
#define GY    4              // 512/128
#define NC    64             // batch*channels
#define NBLK  (GX * GY * NC) // 2048
#define NVT   8              // V tiles per strip (8*16 = 128 rows)
#define NHT   9              // H tiles per strip

typedef float          f32x4  __attribute__((ext_vector_type(4)));
typedef __bf16         bf16x8 __attribute__((ext_vector_type(8)));
typedef __bf16         bf16x4 __attribute__((ext_vector_type(4)));
typedef short          s16x4  __attribute__((ext_vector_type(4)));
typedef unsigned int   u32x2  __attribute__((ext_vector_type(2)));
typedef unsigned int   u32x4  __attribute__((ext_vector_type(4)));

union F8 { bf16x8 v; __bf16 b[8]; u32x4 q; };
union F4 { bf16x4 v; s16x4 s; __bf16 b[4]; u32x2 q; };

__device__ __forceinline__ unsigned short bfbits(float f) {
    __bf16 h = (__bf16)f;
    return __builtin_bit_cast(unsigned short, h);
}

__device__ __forceinline__ f32x4 mfma16(const F4& a, const F4& b, f32x4 c) {
    return __builtin_amdgcn_mfma_f32_16x16x16bf16_1k(a.s, b.s, c, 0, 0, 0);
}

struct GaussW { float g[11]; };

__global__ __launch_bounds__(256, 4) void ssim_mfma_kernel(
    const float* __restrict__ X, const float* __restrict__ Y,
    float* __restrict__ partial, GaussW gw)
{
    __shared__ unsigned short wl[16][40];   // band weights: wl[m][k] = w[k-m]
    __shared__ float wsum[WPB];

    const int tid  = threadIdx.x;
    const int lane = tid & 63;
    const int wave = tid >> 6;
    const int m    = lane & 15;
    const int g    = lane >> 4;

    // ---- weight band LUT (1.25 KB, filled once) ----
    for (int t = tid; t < 16 * 40; t += 256) {
        const int mm = t / 40, kk = t - 40 * mm;
        const int d  = kk - mm;
        wl[mm][kk] = bfbits((kk < 32 && d >= 0 && d < 11) ? gw.g[d] : 0.f);
    }
    __syncthreads();

    const int gx0 = blockIdx.x * BC + SC * wave;   // this wave's strip
    const int gy0 = blockIdx.y * BR;
    const int nc  = blockIdx.z;
    const float* __restrict__ Xp = X + (size_t)nc * IMG * IMG;
    const float* __restrict__ Yp = Y + (size_t)nc * IMG * IMG;

    F8 wf;  wf.q  = *(const u32x4*)&wl[m][8 * g];       // H B-frag: w[8g+j - m]
    F4 wa0; wa0.q = *(const u32x2*)&wl[m][4 * g];       // V A chunk0: w[4g+j - m]
    F4 wa1; wa1.q = *(const u32x2*)&wl[m][16 + 4 * g];  // V A chunk1: w[16+4g+j - m]
    const f32x4 z = {0.f, 0.f, 0.f, 0.f};

    const int cs = min(gx0 + 8 * g, IMG - 8);   // clamped cols feed only masked
                                                // outputs (band is zero there)

    // H stage from by-value raw regs (round-8-proven element-write codegen)
    auto mfmaH = [&](F4 (&hd)[5], f32x4 a0, f32x4 a1, f32x4 b0, f32x4 b1) {
        F8 fx, fy, fxx, fyy, fxy;
#pragma unroll
        for (int j = 0; j < 4; ++j) {
            fx.b[j]      = (__bf16)a0[j];
            fx.b[4 + j]  = (__bf16)a1[j];
            fy.b[j]      = (__bf16)b0[j];
            fy.b[4 + j]  = (__bf16)b1[j];
            fxx.b[j]     = (__bf16)(a0[j] * a0[j]);
            fxx.b[4 + j] = (__bf16)(a1[j] * a1[j]);
            fyy.b[j]     = (__bf16)(b0[j] * b0[j]);
            fyy.b[4 + j] = (__bf16)(b1[j] * b1[j]);
            fxy.b[j]     = (__bf16)(a0[j] * b0[j]);
            fxy.b[4 + j] = (__bf16)(a1[j] * b1[j]);
        }
        const f32x4 dX  = __builtin_amdgcn_mfma_f32_16x16x32_bf16(fx.v,  wf.v, z, 0, 0, 0);
        const f32x4 dY  = __builtin_amdgcn_mfma_f32_16x16x32_bf16(fy.v,  wf.v, z, 0, 0, 0);
        const f32x4 dXX = __builtin_amdgcn_mfma_f32_16x16x32_bf16(fxx.v, wf.v, z, 0, 0, 0);
        const f32x4 dYY = __builtin_amdgcn_mfma_f32_16x16x32_bf16(fyy.v, wf.v, z, 0, 0, 0);
        const f32x4 dXY = __builtin_amdgcn_mfma_f32_16x16x32_bf16(fxy.v, wf.v, z, 0, 0, 0);
#pragma unroll
        for (int i = 0; i < 4; ++i) {
            hd[0].b[i] = (__bf16)dX[i];
            hd[1].b[i] = (__bf16)dY[i];
            hd[2].b[i] = (__bf16)dXX[i];
            hd[3].b[i] = (__bf16)dYY[i];
            hd[4].b[i] = (__bf16)dXY[i];
        }
    };

    float acc = 0.f;
    // V stage + SSIM epilogue for output tile vt (literal), rows from h0,h1
    auto vstage = [&](const F4 (&h0)[5], const F4 (&h1)[5], int vt) {
        f32x4 e[5];
#pragma unroll
        for (int q = 0; q < 5; ++q) {
            e[q] = mfma16(wa1, h1[q], z);
            e[q] = mfma16(wa0, h0[q], e[q]);
        }
        const float C1 = 1e-4f, C2 = 9e-4f;
#pragma unroll
        for (int i = 0; i < 4; ++i) {
            const int gy = gy0 + 16 * vt + 4 * g + i;
            const int gx = gx0 + m;
            const float mX = e[0][i], mY = e[1][i];
            const float muXX = mX * mX;
            const float muYY = mY * mY;
            const float muXY = mX * mY;
            const float sXX = e[2][i] - muXX;
            const float sYY = e[3][i] - muYY;
            const float sXY = e[4][i] - muXY;
            const float num = (2.f * muXY + C1) * (2.f * sXY + C2);
            const float den = (muXX + muYY + C1) * (sXX + sYY + C2);
            const float val = __fdividef(num, den);
            if (gy < ODIM && gx < ODIM) acc += val;
        }
    };

    // ---- 3-stage pipeline with NAMED raw buffers (no arrays -> no scratch) --
    f32x4 xA0, xA1, yA0, yA1;    // raw buffer A
    f32x4 xB0, xB1, yB0, yB1;    // raw buffer B
    F4 hA[5], hB[5];

#define LOADRAW(rt, X0, X1, Y0, Y1) do {                        \
        const int gy_ = min(gy0 + 16 * (rt) + m, IMG - 1);      \
        const float* xr_ = Xp + gy_ * IMG + cs;                 \
        const float* yr_ = Yp + gy_ * IMG + cs;                 \
        X0 = *(const f32x4*)xr_;  X1 = *(const f32x4*)(xr_ + 4);\
        Y0 = *(const f32x4*)yr_;  Y1 = *(const f32x4*)(yr_ + 4);\
    } while (0)

    LOADRAW(0, xA0, xA1, yA0, yA1);
    LOADRAW(1, xB0, xB1, yB0, yB1);
    mfmaH(hA, xA0, xA1, yA0, yA1);

    // even vt: prefetch into A (its H already consumed), H(B)->hB, V(hA,hB)
#define STEP_E(vt) do {                                         \
        if ((vt) + 2 < NHT) LOADRAW((vt) + 2, xA0, xA1, yA0, yA1); \
        mfmaH(hB, xB0, xB1, yB0, yB1);                          \
        vstage(hA, hB, (vt));                                   \
    } while (0)
    // odd vt: prefetch into B, H(A)->hA, V(hB,hA)
#define STEP_O(vt) do {                                         \
        if ((vt) + 2 < NHT) LOADRAW((vt) + 2, xB0, xB1, yB0, yB1); \
        mfmaH(hA, xA0, xA1, yA0, yA1);                          \
        vstage(hB, hA, (vt));                                   \
    } while (0)

    STEP_E(0); STEP_O(1); STEP_E(2); STEP_O(3);
    STEP_E(4); STEP_O(5); STEP_E(6); STEP_O(7);
#undef STEP_E
#undef STEP_O
#undef LOADRAW

    // ---- deterministic block reduction ----
#pragma unroll
    for (int off = 32; off > 0; off >>= 1)
        acc += __shfl_down(acc, off, 64);

    if (lane == 0) wsum[wave] = acc;
    __syncthreads();
    if (tid == 0) {
        const float tsum = (wsum[0] + wsum[1]) + (wsum[2] + wsum[3]);
        partial[((size_t)blockIdx.z * gridDim.y + blockIdx.y) * gridDim.x + blockIdx.x] = tsum;
    }
}

__global__ __launch_bounds__(512) void ssim_finish_kernel(
    const float* __restrict__ partial, float* __restrict__ out)
{
    __shared__ double sd[512];
    const float4* p4 = (const float4*)partial;   // NBLK = 2048 = 512*4
    const float4 v = p4[threadIdx.x];
    double local = ((double)v.x + (double)v.y) + ((double)v.z + (double)v.w);
    sd[threadIdx.x] = local;
    __syncthreads();
    for (int s = 256; s > 0; s >>= 1) {
        if (threadIdx.x < s) sd[threadIdx.x] += sd[threadIdx.x + s];
        __syncthreads();
    }
    if (threadIdx.x == 0) {
        const double cnt = (double)NC * (double)ODIM * (double)ODIM;
        out[0] = (float)(1.0 - sd[0] / cnt);
    }
}

extern "C" void kernel_launch(void* const* d_in, const int* in_sizes, int n_in,
                              void* d_out, int out_size, void* d_ws, size_t ws_size,
                              hipStream_t stream) {
    const float* X = (const float*)d_in[0];
    const float* Y = (const float*)d_in[1];
    float* out = (float*)d_out;
    float* partial = (float*)d_ws;   // NBLK floats = 8 KiB

    // Gaussian taps in float64 -> f32 (matches numpy reference construction).
    GaussW gw;
    {
        double gd[11], s = 0.0;
        for (int i = 0; i < 11; ++i) {
            const double x = (double)(i - 5);
            gd[i] = std::exp(-(x * x) / (2.0 * 1.5 * 1.5));
            s += gd[i];
        }
        for (int i = 0; i < 11; ++i) gw.g[i] = (float)(gd[i] / s);
    }

    dim3 grid(GX, GY, NC);
    ssim_mfma_kernel<<<grid, 256, 0, stream>>>(X, Y, partial, gw);
    ssim_finish_kernel<<<1, 512, 0, stream>>>(partial, out);
}

// Round 12
// 45.647 us; speedup vs baseline: 2.5507x; 1.0317x over previous
//
#include <hip/hip_runtime.h>
#include <hip/hip_bf16.h>
#include <cmath>

// SSIM loss via MFMA, round 12: round-11 structure + packed-math codegen.
// H pass: 16x16x32 bf16 MFMA (A=data rows, B=banded Gaussian W).
// H's D-layout (lane: rows 4g+i, col m) IS the B-frag layout of a K=16 MFMA
// (lane: k=4g+j, col m), so V = 2 chained mfma_16x16x16_bf16 per quantity with
// B-frags straight from H result registers. No hq LDS, no mid-kernel barrier.
// vs round 11 (47us, VALU-busy ~28us vs ~10us bottom-up -> codegen bloat):
//  - squares/products and the whole SSIM epilogue as f32x4 VECTOR expressions
//    (v_pk_mul_f32 / v_pk_add_f32 / v_pk_fma_f32: 2 inst per 4 lanes-of-4)
//  - f32x4 accumulator, one fixed-order reduce at the end (deterministic)
//  - row clamp only on tile 8 (tiles 0..7 provably never clamp: max gy=511),
//    folded at compile time via literal-rt macro

#define IMG   512
#define ODIM  502            // 512 - 11 + 1
#define SC    16             // strip cols (per wave)
#define BR    128            // strip rows
#define WPB   4              // waves per block
#define BC    (SC * WPB)     // 64 block cols
#define GX    8              // 512/64
#define GY    4              // 512/128
#define NC    64             // batch*channels
#define NBLK  (GX * GY * NC) // 2048
#define NVT   8              // V tiles per strip (8*16 = 128 rows)
#define NHT   9              // H tiles per strip

typedef float          f32x4  __attribute__((ext_vector_type(4)));
typedef __bf16         bf16x8 __attribute__((ext_vector_type(8)));
typedef __bf16         bf16x4 __attribute__((ext_vector_type(4)));
typedef short          s16x4  __attribute__((ext_vector_type(4)));
typedef unsigned int   u32x2  __attribute__((ext_vector_type(2)));
typedef unsigned int   u32x4  __attribute__((ext_vector_type(4)));
typedef int            i32x4  __attribute__((ext_vector_type(4)));

union F8 { bf16x8 v; __bf16 b[8]; u32x4 q; };
union F4 { bf16x4 v; s16x4 s; __bf16 b[4]; u32x2 q; };

__device__ __forceinline__ unsigned short bfbits(float f) {
    __bf16 h = (__bf16)f;
    return __builtin_bit_cast(unsigned short, h);
}

__device__ __forceinline__ f32x4 mfma16(const F4& a, const F4& b, f32x4 c) {
    return __builtin_amdgcn_mfma_f32_16x16x16bf16_1k(a.s, b.s, c, 0, 0, 0);
}

struct GaussW { float g[11]; };

__global__ __launch_bounds__(256, 4) void ssim_mfma_kernel(
    const float* __restrict__ X, const float* __restrict__ Y,
    float* __restrict__ partial, GaussW gw)
{
    __shared__ unsigned short wl[16][40];   // band weights: wl[m][k] = w[k-m]
    __shared__ float wsum[WPB];

    const int tid  = threadIdx.x;
    const int lane = tid & 63;
    const int wave = tid >> 6;
    const int m    = lane & 15;
    const int g    = lane >> 4;

    // ---- weight band LUT (1.25 KB, filled once) ----
    for (int t = tid; t < 16 * 40; t += 256) {
        const int mm = t / 40, kk = t - 40 * mm;
        const int d  = kk - mm;
        wl[mm][kk] = bfbits((kk < 32 && d >= 0 && d < 11) ? gw.g[d] : 0.f);
    }
    __syncthreads();

    const int gx0 = blockIdx.x * BC + SC * wave;   // this wave's strip
    const int gy0 = blockIdx.y * BR;
    const int nc  = blockIdx.z;
    const float* __restrict__ Xp = X + (size_t)nc * IMG * IMG;
    const float* __restrict__ Yp = Y + (size_t)nc * IMG * IMG;

    F8 wf;  wf.q  = *(const u32x4*)&wl[m][8 * g];       // H B-frag: w[8g+j - m]
    F4 wa0; wa0.q = *(const u32x2*)&wl[m][4 * g];       // V A chunk0: w[4g+j - m]
    F4 wa1; wa1.q = *(const u32x2*)&wl[m][16 + 4 * g];  // V A chunk1: w[16+4g+j - m]
    const f32x4 z = {0.f, 0.f, 0.f, 0.f};

    const int cs = min(gx0 + 8 * g, IMG - 8);   // clamped cols feed only masked
                                                // outputs (band is zero there)
    const float* __restrict__ xbase = Xp + (gy0 + m) * IMG + cs;
    const float* __restrict__ ybase = Yp + (gy0 + m) * IMG + cs;

    // H stage from by-value raw regs; squares via f32x4 vector ops (pk_mul)
    auto mfmaH = [&](F4 (&hd)[5], f32x4 a0, f32x4 a1, f32x4 b0, f32x4 b1) {
        const f32x4 xx0 = a0 * a0, xx1 = a1 * a1;
        const f32x4 yy0 = b0 * b0, yy1 = b1 * b1;
        const f32x4 xy0 = a0 * b0, xy1 = a1 * b1;
        F8 fx, fy, fxx, fyy, fxy;
#pragma unroll
        for (int j = 0; j < 4; ++j) {
            fx.b[j]      = (__bf16)a0[j];
            fx.b[4 + j]  = (__bf16)a1[j];
            fy.b[j]      = (__bf16)b0[j];
            fy.b[4 + j]  = (__bf16)b1[j];
            fxx.b[j]     = (__bf16)xx0[j];
            fxx.b[4 + j] = (__bf16)xx1[j];
            fyy.b[j]     = (__bf16)yy0[j];
            fyy.b[4 + j] = (__bf16)yy1[j];
            fxy.b[j]     = (__bf16)xy0[j];
            fxy.b[4 + j] = (__bf16)xy1[j];
        }
        const f32x4 dX  = __builtin_amdgcn_mfma_f32_16x16x32_bf16(fx.v,  wf.v, z, 0, 0, 0);
        const f32x4 dY  = __builtin_amdgcn_mfma_f32_16x16x32_bf16(fy.v,  wf.v, z, 0, 0, 0);
        const f32x4 dXX = __builtin_amdgcn_mfma_f32_16x16x32_bf16(fxx.v, wf.v, z, 0, 0, 0);
        const f32x4 dYY = __builtin_amdgcn_mfma_f32_16x16x32_bf16(fyy.v, wf.v, z, 0, 0, 0);
        const f32x4 dXY = __builtin_amdgcn_mfma_f32_16x16x32_bf16(fxy.v, wf.v, z, 0, 0, 0);
#pragma unroll
        for (int i = 0; i < 4; ++i) {
            hd[0].b[i] = (__bf16)dX[i];
            hd[1].b[i] = (__bf16)dY[i];
            hd[2].b[i] = (__bf16)dXX[i];
            hd[3].b[i] = (__bf16)dYY[i];
            hd[4].b[i] = (__bf16)dXY[i];
        }
    };

    f32x4 vacc = z;                       // packed accumulator (fixed order)
    const int gxv   = gx0 + m;            // this lane's output col
    const bool colok = (gxv < ODIM);

    // V stage + vectorized SSIM epilogue for output tile vt (literal)
    auto vstage = [&](const F4 (&h0)[5], const F4 (&h1)[5], int vt) {
        f32x4 e[5];
#pragma unroll
        for (int q = 0; q < 5; ++q) {
            e[q] = mfma16(wa1, h1[q], z);
            e[q] = mfma16(wa0, h0[q], e[q]);
        }
        const float C1 = 1e-4f, C2 = 9e-4f;
        const f32x4 mX = e[0], mY = e[1];
        const f32x4 muXX = mX * mX;
        const f32x4 muYY = mY * mY;
        const f32x4 muXY = mX * mY;
        const f32x4 sXX = e[2] - muXX;
        const f32x4 sYY = e[3] - muYY;
        const f32x4 sXY = e[4] - muXY;
        const f32x4 num = (2.f * muXY + C1) * (2.f * sXY + C2);
        const f32x4 den = (muXX + muYY + C1) * (sXX + sYY + C2);
        f32x4 val;
#pragma unroll
        for (int i = 0; i < 4; ++i) val[i] = __fdividef(num[i], den[i]);
        const int gyb = gy0 + 16 * vt + 4 * g;   // rows gyb..gyb+3
#pragma unroll
        for (int i = 0; i < 4; ++i)
            vacc[i] += (colok && (gyb + i < ODIM)) ? val[i] : 0.f;
    };

    // ---- 3-stage pipeline with NAMED raw buffers (no arrays -> no scratch) --
    f32x4 xA0, xA1, yA0, yA1;    // raw buffer A
    f32x4 xB0, xB1, yB0, yB1;    // raw buffer B
    F4 hA[5], hB[5];

    // tiles 0..7 never clamp (max gy = 384+112+15 = 511); tile 8 clamps.
#define LOADRAW(rt, X0, X1, Y0, Y1) do {                                   \
        const float* xr_;  const float* yr_;                               \
        if ((rt) < 8) {                                                    \
            xr_ = xbase + (rt) * 16 * IMG;                                 \
            yr_ = ybase + (rt) * 16 * IMG;                                 \
        } else {                                                           \
            const int gy_ = min(gy0 + 16 * (rt) + m, IMG - 1);             \
            xr_ = Xp + gy_ * IMG + cs;                                     \
            yr_ = Yp + gy_ * IMG + cs;                                     \
        }                                                                  \
        X0 = *(const f32x4*)xr_;  X1 = *(const f32x4*)(xr_ + 4);           \
        Y0 = *(const f32x4*)yr_;  Y1 = *(const f32x4*)(yr_ + 4);           \
    } while (0)

    LOADRAW(0, xA0, xA1, yA0, yA1);
    LOADRAW(1, xB0, xB1, yB0, yB1);
    mfmaH(hA, xA0, xA1, yA0, yA1);

    // even vt: prefetch into A (its H already consumed), H(B)->hB, V(hA,hB)
#define STEP_E(vt) do {                                                    \
        if ((vt) + 2 < NHT) LOADRAW((vt) + 2, xA0, xA1, yA0, yA1);         \
        mfmaH(hB, xB0, xB1, yB0, yB1);                                     \
        vstage(hA, hB, (vt));                                              \
    } while (0)
    // odd vt: prefetch into B, H(A)->hA, V(hB,hA)
#define STEP_O(vt) do {                                                    \
        if ((vt) + 2 < NHT) LOADRAW((vt) + 2, xB0, xB1, yB0, yB1);         \
        mfmaH(hA, xA0, xA1, yA0, yA1);                                     \
        vstage(hB, hA, (vt));                                              \
    } while (0)

    STEP_E(0); STEP_O(1); STEP_E(2); STEP_O(3);
    STEP_E(4); STEP_O(5); STEP_E(6); STEP_O(7);
#undef STEP_E
#undef STEP_O
#undef LOADRAW

    // ---- deterministic reductions: vec4 -> lane -> wave -> block ----
    float acc = (vacc[0] + vacc[1]) + (vacc[2] + vacc[3]);
#pragma unroll
    for (int off = 32; off > 0; off >>= 1)
        acc += __shfl_down(acc, off, 64);

    if (lane == 0) wsum[wave] = acc;
    __syncthreads();
    if (tid == 0) {
        const float tsum = (wsum[0] + wsum[1]) + (wsum[2] + wsum[3]);
        partial[((size_t)blockIdx.z * gridDim.y + blockIdx.y) * gridDim.x + blockIdx.x] = tsum;
    }
}

__global__ __launch_bounds__(512) void ssim_finish_kernel(
    const float* __restrict__ partial, float* __restrict__ out)
{
    __shared__ double sd[512];
    const float4* p4 = (const float4*)partial;   // NBLK = 2048 = 512*4
    const float4 v = p4[threadIdx.x];
    double local = ((double)v.x + (double)v.y) + ((double)v.z + (double)v.w);
    sd[threadIdx.x] = local;
    __syncthreads();
    for (int s = 256; s > 0; s >>= 1) {
        if (threadIdx.x < s) sd[threadIdx.x] += sd[threadIdx.x + s];
        __syncthreads();
    }
    if (threadIdx.x == 0) {
        const double cnt = (double)NC * (double)ODIM * (double)ODIM;
        out[0] = (float)(1.0 - sd[0] / cnt);
    }
}

extern "C" void kernel_launch(void* const* d_in, const int* in_sizes, int n_in,
                              void* d_out, int out_size, void* d_ws, size_t ws_size,
                              hipStream_t stream) {
    const float* X = (const float*)d_in[0];
    const float* Y = (const float*)d_in[1];
    float* out = (float*)d_out;
    float* partial = (float*)d_ws;   // NBLK floats = 8 KiB

    // Gaussian taps in float64 -> f32 (matches numpy reference construction).
    GaussW gw;
    {
        double gd[11], s = 0.0;
        for (int i = 0; i < 11; ++i) {
            const double x = (double)(i - 5);
            gd[i] = std::exp(-(x * x) / (2.0 * 1.5 * 1.5));
            s += gd[i];
        }
        for (int i = 0; i < 11; ++i) gw.g[i] = (float)(gd[i] / s);
    }

    dim3 grid(GX, GY, NC);
    ssim_mfma_kernel<<<grid, 256, 0, stream>>>(X, Y, partial, gw);
    ssim_finish_kernel<<<1, 512, 0, stream>>>(partial, out);
}

// Round 13
// 44.670 us; speedup vs baseline: 2.6065x; 1.0219x over previous
//
#include <hip/hip_runtime.h>
#include <hip/hip_bf16.h>
#include <cmath>

// SSIM loss via MFMA, round 13: 3-phase rotating software pipeline.
// H pass: 16x16x32 bf16 MFMA (A=data rows, B=banded Gaussian W).
// H's D-layout (lane: rows 4g+i, col m) IS the B-frag layout of a K=16 MFMA
// (lane: k=4g+j, col m), so V = 2 chained mfma_16x16x16_bf16 per quantity with
// B-frags straight from H result registers. No hq LDS, no mid-kernel barrier.
// vs round 12 (45.6us, latency-bound): the old step body was a SERIAL chain
// (load -> H-MFMA -> immediately consume in V). Now 3 raw buffers + 3 h slots
// rotate so each step's {load(t+3), H(t+2), V(t)} are mutually independent:
//   prologue: L0,L1,L2, H0, H1
//   step t:   L(t+3) | H(t+2) from raw loaded 1 step ago | V(t) from h(t),h(t+1)
// Slot algebra (tile k -> slot k%3) hand-verified below.

#define IMG   512
#define ODIM  502            // 512 - 11 + 1
#define SC    16             // strip cols (per wave)
#define BR    128            // strip rows
#define WPB   4              // waves per block
#define BC    (SC * WPB)     // 64 block cols
#define GX    8              // 512/64
#define GY    4              // 512/128
#define NC    64             // batch*channels
#define NBLK  (GX * GY * NC) // 2048
#define NVT   8              // V tiles per strip (8*16 = 128 rows)
#define NHT   9              // H tiles per strip

typedef float          f32x4  __attribute__((ext_vector_type(4)));
typedef __bf16         bf16x8 __attribute__((ext_vector_type(8)));
typedef __bf16         bf16x4 __attribute__((ext_vector_type(4)));
typedef short          s16x4  __attribute__((ext_vector_type(4)));
typedef unsigned int   u32x2  __attribute__((ext_vector_type(2)));
typedef unsigned int   u32x4  __attribute__((ext_vector_type(4)));

union F8 { bf16x8 v; __bf16 b[8]; u32x4 q; };
union F4 { bf16x4 v; s16x4 s; __bf16 b[4]; u32x2 q; };

__device__ __forceinline__ unsigned short bfbits(float f) {
    __bf16 h = (__bf16)f;
    return __builtin_bit_cast(unsigned short, h);
}

__device__ __forceinline__ f32x4 mfma16(const F4& a, const F4& b, f32x4 c) {
    return __builtin_amdgcn_mfma_f32_16x16x16bf16_1k(a.s, b.s, c, 0, 0, 0);
}

struct GaussW { float g[11]; };

__global__ __launch_bounds__(256, 4) void ssim_mfma_kernel(
    const float* __restrict__ X, const float* __restrict__ Y,
    float* __restrict__ partial, GaussW gw)
{
    __shared__ unsigned short wl[16][40];   // band weights: wl[m][k] = w[k-m]
    __shared__ float wsum[WPB];

    const int tid  = threadIdx.x;
    const int lane = tid & 63;
    const int wave = tid >> 6;
    const int m    = lane & 15;
    const int g    = lane >> 4;

    // ---- weight band LUT (1.25 KB, filled once) ----
    for (int t = tid; t < 16 * 40; t += 256) {
        const int mm = t / 40, kk = t - 40 * mm;
        const int d  = kk - mm;
        wl[mm][kk] = bfbits((kk < 32 && d >= 0 && d < 11) ? gw.g[d] : 0.f);
    }
    __syncthreads();

    const int gx0 = blockIdx.x * BC + SC * wave;   // this wave's strip
    const int gy0 = blockIdx.y * BR;
    const int nc  = blockIdx.z;
    const float* __restrict__ Xp = X + (size_t)nc * IMG * IMG;
    const float* __restrict__ Yp = Y + (size_t)nc * IMG * IMG;

    F8 wf;  wf.q  = *(const u32x4*)&wl[m][8 * g];       // H B-frag: w[8g+j - m]
    F4 wa0; wa0.q = *(const u32x2*)&wl[m][4 * g];       // V A chunk0: w[4g+j - m]
    F4 wa1; wa1.q = *(const u32x2*)&wl[m][16 + 4 * g];  // V A chunk1: w[16+4g+j - m]
    const f32x4 z = {0.f, 0.f, 0.f, 0.f};

    const int cs = min(gx0 + 8 * g, IMG - 8);   // clamped cols feed only masked
                                                // outputs (band is zero there)
    const float* __restrict__ xbase = Xp + (gy0 + m) * IMG + cs;
    const float* __restrict__ ybase = Yp + (gy0 + m) * IMG + cs;

    // H stage from by-value raw regs; squares via f32x4 vector ops (pk_mul)
    auto mfmaH = [&](F4 (&hd)[5], f32x4 a0, f32x4 a1, f32x4 b0, f32x4 b1) {
        const f32x4 xx0 = a0 * a0, xx1 = a1 * a1;
        const f32x4 yy0 = b0 * b0, yy1 = b1 * b1;
        const f32x4 xy0 = a0 * b0, xy1 = a1 * b1;
        F8 fx, fy, fxx, fyy, fxy;
#pragma unroll
        for (int j = 0; j < 4; ++j) {
            fx.b[j]      = (__bf16)a0[j];
            fx.b[4 + j]  = (__bf16)a1[j];
            fy.b[j]      = (__bf16)b0[j];
            fy.b[4 + j]  = (__bf16)b1[j];
            fxx.b[j]     = (__bf16)xx0[j];
            fxx.b[4 + j] = (__bf16)xx1[j];
            fyy.b[j]     = (__bf16)yy0[j];
            fyy.b[4 + j] = (__bf16)yy1[j];
            fxy.b[j]     = (__bf16)xy0[j];
            fxy.b[4 + j] = (__bf16)xy1[j];
        }
        const f32x4 dX  = __builtin_amdgcn_mfma_f32_16x16x32_bf16(fx.v,  wf.v, z, 0, 0, 0);
        const f32x4 dY  = __builtin_amdgcn_mfma_f32_16x16x32_bf16(fy.v,  wf.v, z, 0, 0, 0);
        const f32x4 dXX = __builtin_amdgcn_mfma_f32_16x16x32_bf16(fxx.v, wf.v, z, 0, 0, 0);
        const f32x4 dYY = __builtin_amdgcn_mfma_f32_16x16x32_bf16(fyy.v, wf.v, z, 0, 0, 0);
        const f32x4 dXY = __builtin_amdgcn_mfma_f32_16x16x32_bf16(fxy.v, wf.v, z, 0, 0, 0);
#pragma unroll
        for (int i = 0; i < 4; ++i) {
            hd[0].b[i] = (__bf16)dX[i];
            hd[1].b[i] = (__bf16)dY[i];
            hd[2].b[i] = (__bf16)dXX[i];
            hd[3].b[i] = (__bf16)dYY[i];
            hd[4].b[i] = (__bf16)dXY[i];
        }
    };

    f32x4 vacc = z;                       // packed accumulator (fixed order)
    const int gxv   = gx0 + m;            // this lane's output col
    const bool colok = (gxv < ODIM);

    // V stage + vectorized SSIM epilogue for output tile vt (literal)
    auto vstage = [&](const F4 (&h0)[5], const F4 (&h1)[5], int vt) {
        f32x4 e[5];
#pragma unroll
        for (int q = 0; q < 5; ++q) {
            e[q] = mfma16(wa1, h1[q], z);
            e[q] = mfma16(wa0, h0[q], e[q]);
        }
        const float C1 = 1e-4f, C2 = 9e-4f;
        const f32x4 mX = e[0], mY = e[1];
        const f32x4 muXX = mX * mX;
        const f32x4 muYY = mY * mY;
        const f32x4 muXY = mX * mY;
        const f32x4 sXX = e[2] - muXX;
        const f32x4 sYY = e[3] - muYY;
        const f32x4 sXY = e[4] - muXY;
        const f32x4 num = (2.f * muXY + C1) * (2.f * sXY + C2);
        const f32x4 den = (muXX + muYY + C1) * (sXX + sYY + C2);
        f32x4 val;
#pragma unroll
        for (int i = 0; i < 4; ++i) val[i] = __fdividef(num[i], den[i]);
        const int gyb = gy0 + 16 * vt + 4 * g;   // rows gyb..gyb+3
#pragma unroll
        for (int i = 0; i < 4; ++i)
            vacc[i] += (colok && (gyb + i < ODIM)) ? val[i] : 0.f;
    };

    // ---- 3-phase pipeline: named raw trios A/B/C, h slots h0/h1/h2 ----
    f32x4 xA0, xA1, yA0, yA1;
    f32x4 xB0, xB1, yB0, yB1;
    f32x4 xC0, xC1, yC0, yC1;
    F4 h0[5], h1[5], h2[5];

    // tiles 0..7 never clamp (max gy = 384+112+15 = 511); tile 8 clamps.
#define LOADRAW(rt, X0, X1, Y0, Y1) do {                                   \
        const float* xr_;  const float* yr_;                               \
        if ((rt) < 8) {                                                    \
            xr_ = xbase + (rt) * 16 * IMG;                                 \
            yr_ = ybase + (rt) * 16 * IMG;                                 \
        } else {                                                           \
            const int gy_ = min(gy0 + 16 * (rt) + m, IMG - 1);             \
            xr_ = Xp + gy_ * IMG + cs;                                     \
            yr_ = Yp + gy_ * IMG + cs;                                     \
        }                                                                  \
        X0 = *(const f32x4*)xr_;  X1 = *(const f32x4*)(xr_ + 4);           \
        Y0 = *(const f32x4*)yr_;  Y1 = *(const f32x4*)(yr_ + 4);           \
    } while (0)

    // prologue: 3 tile-loads in flight, then H(0), H(1)
    LOADRAW(0, xA0, xA1, yA0, yA1);
    LOADRAW(1, xB0, xB1, yB0, yB1);
    LOADRAW(2, xC0, xC1, yC0, yC1);
    mfmaH(h0, xA0, xA1, yA0, yA1);          // tile 0 -> slot 0
    mfmaH(h1, xB0, xB1, yB0, yB1);          // tile 1 -> slot 1

    // step t: L(t+3) | H(t+2) | V(t).  tile k lives in raw/h slot k%3.
    LOADRAW(3, xA0, xA1, yA0, yA1);  mfmaH(h2, xC0, xC1, yC0, yC1);  vstage(h0, h1, 0);
    LOADRAW(4, xB0, xB1, yB0, yB1);  mfmaH(h0, xA0, xA1, yA0, yA1);  vstage(h1, h2, 1);
    LOADRAW(5, xC0, xC1, yC0, yC1);  mfmaH(h1, xB0, xB1, yB0, yB1);  vstage(h2, h0, 2);
    LOADRAW(6, xA0, xA1, yA0, yA1);  mfmaH(h2, xC0, xC1, yC0, yC1);  vstage(h0, h1, 3);
    LOADRAW(7, xB0, xB1, yB0, yB1);  mfmaH(h0, xA0, xA1, yA0, yA1);  vstage(h1, h2, 4);
    LOADRAW(8, xC0, xC1, yC0, yC1);  mfmaH(h1, xB0, xB1, yB0, yB1);  vstage(h2, h0, 5);
                                     mfmaH(h2, xC0, xC1, yC0, yC1);  vstage(h0, h1, 6);
                                                                     vstage(h1, h2, 7);
#undef LOADRAW

    // ---- deterministic reductions: vec4 -> lane -> wave -> block ----
    float acc = (vacc[0] + vacc[1]) + (vacc[2] + vacc[3]);
#pragma unroll
    for (int off = 32; off > 0; off >>= 1)
        acc += __shfl_down(acc, off, 64);

    if (lane == 0) wsum[wave] = acc;
    __syncthreads();
    if (tid == 0) {
        const float tsum = (wsum[0] + wsum[1]) + (wsum[2] + wsum[3]);
        partial[((size_t)blockIdx.z * gridDim.y + blockIdx.y) * gridDim.x + blockIdx.x] = tsum;
    }
}

__global__ __launch_bounds__(512) void ssim_finish_kernel(
    const float* __restrict__ partial, float* __restrict__ out)
{
    __shared__ double sd[512];
    const float4* p4 = (const float4*)partial;   // NBLK = 2048 = 512*4
    const float4 v = p4[threadIdx.x];
    double local = ((double)v.x + (double)v.y) + ((double)v.z + (double)v.w);
    sd[threadIdx.x] = local;
    __syncthreads();
    for (int s = 256; s > 0; s >>= 1) {
        if (threadIdx.x < s) sd[threadIdx.x] += sd[threadIdx.x + s];
        __syncthreads();
    }
    if (threadIdx.x == 0) {
        const double cnt = (double)NC * (double)ODIM * (double)ODIM;
        out[0] = (float)(1.0 - sd[0] / cnt);
    }
}

extern "C" void kernel_launch(void* const* d_in, const int* in_sizes, int n_in,
                              void* d_out, int out_size, void* d_ws, size_t ws_size,
                              hipStream_t stream) {
    const float* X = (const float*)d_in[0];
    const float* Y = (const float*)d_in[1];
    float* out = (float*)d_out;
    float* partial = (float*)d_ws;   // NBLK floats = 8 KiB

    // Gaussian taps in float64 -> f32 (matches numpy reference construction).
    GaussW gw;
    {
        double gd[11], s = 0.0;
        for (int i = 0; i < 11; ++i) {
            const double x = (double)(i - 5);
            gd[i] = std::exp(-(x * x) / (2.0 * 1.5 * 1.5));
            s += gd[i];
        }
        for (int i = 0; i < 11; ++i) gw.g[i] = (float)(gd[i] / s);
    }

    dim3 grid(GX, GY, NC);
    ssim_mfma_kernel<<<grid, 256, 0, stream>>>(X, Y, partial, gw);
    ssim_finish_kernel<<<1, 512, 0, stream>>>(partial, out);
}